// Round 7
// baseline (905.440 us; speedup 1.0000x reference)
//
#include <hip/hip_runtime.h>
#include <hip/hip_bf16.h>
#include <math.h>

// GoldenMoE: B=2,T=2048,D=2048,E=8,F=2048.
// Round 7: r6 8-phase skeleton unchanged; MFMA switched from inline-asm "+v"
// (which forced v_accvgpr shuttling, ~1000 VALU ops/iter) to the builtin
// __builtin_amdgcn_mfma_f32_16x16x32_bf16 (acc lives in AGPRs natively).

#define E_NUM 8
#define BT_NUM 4096
#define MAT_ELEMS ((size_t)2048 * 2048)

typedef short short8 __attribute__((ext_vector_type(8)));
typedef float f32x4 __attribute__((ext_vector_type(4)));
typedef __bf16 bf16x8 __attribute__((ext_vector_type(8)));

__device__ __forceinline__ short f2bf(float f) {
  __hip_bfloat16 h = __float2bfloat16(f);
  return __builtin_bit_cast(short, h);
}

#define GLOAD_LDS(gptr, lptr) \
  __builtin_amdgcn_global_load_lds( \
      (const __attribute__((address_space(1))) unsigned int*)(gptr), \
      (__attribute__((address_space(3))) unsigned int*)(lptr), 16, 0, 0)

#define LDS_OFF(p) ((unsigned)(size_t)(__attribute__((address_space(3))) const short*)(p))

#define DS_READ_B128(d, a) \
  asm volatile("ds_read_b128 %0, %1" : "=v"(d) : "v"(a))

#define BAR() __builtin_amdgcn_s_barrier()
#define LGKM0() do { \
  asm volatile("s_waitcnt lgkmcnt(0)" ::: "memory"); \
  __builtin_amdgcn_sched_barrier(0); \
} while (0)
#define VMC(n) asm volatile("s_waitcnt vmcnt(" #n ")" ::: "memory")

// ---------------- router ----------------
__global__ __launch_bounds__(256) void router_kernel(
    const float* __restrict__ x, const float* __restrict__ Wr,
    const float* __restrict__ temp, float* __restrict__ rw)
{
  const int bt = blockIdx.x;
  const int tid = threadIdx.x;
  const float* xp = x + (size_t)bt * 2048;
  float acc[E_NUM];
#pragma unroll
  for (int e = 0; e < E_NUM; e++) acc[e] = 0.f;
  for (int d = tid; d < 2048; d += 256) {
    float xv = xp[d];
    const float* wr = Wr + (size_t)d * E_NUM;
#pragma unroll
    for (int e = 0; e < E_NUM; e++) acc[e] += xv * wr[e];
  }
#pragma unroll
  for (int e = 0; e < E_NUM; e++) {
    float v = acc[e];
#pragma unroll
    for (int off = 32; off > 0; off >>= 1) v += __shfl_down(v, off, 64);
    acc[e] = v;
  }
  __shared__ float part[4][E_NUM];
  const int wid = tid >> 6, lane = tid & 63;
  if (lane == 0) {
#pragma unroll
    for (int e = 0; e < E_NUM; e++) part[wid][e] = acc[e];
  }
  __syncthreads();
  if (tid == 0) {
    const float t = temp[0];
    float wz[E_NUM], fb[E_NUM];
    float wsum = 0.f;
#pragma unroll
    for (int e = 0; e < E_NUM; e++) {
      float l = part[0][e] + part[1][e] + part[2][e] + part[3][e];
      float ih = 1.f / (1.f + expf(-l / t));
      float ds = fabsf(ih - 0.36787944117144233f);
      float in_zone = (ih >= 0.21231792754821915f && ih <= 0.5f) ? 1.f : 0.f;
      wz[e] = expf(-ds / 0.1f) * in_zone;
      wsum += wz[e];
      fb[e] = expf(-ds / 0.3f);
    }
    float w[E_NUM];
    if (wsum < 1e-8f) {
      int i1 = 0;
#pragma unroll
      for (int e = 1; e < E_NUM; e++) if (fb[e] > fb[i1]) i1 = e;
      int i2 = -1;
#pragma unroll
      for (int e = 0; e < E_NUM; e++) if (e != i1 && (i2 < 0 || fb[e] > fb[i2])) i2 = e;
      float s = fmaxf(fb[i1] + fb[i2], 1e-8f);
#pragma unroll
      for (int e = 0; e < E_NUM; e++) w[e] = (e == i1 || e == i2) ? fb[e] / s : 0.f;
    } else {
#pragma unroll
      for (int e = 0; e < E_NUM; e++) w[e] = wz[e];
    }
    float s2 = 0.f;
#pragma unroll
    for (int e = 0; e < E_NUM; e++) s2 += w[e];
    s2 = fmaxf(s2, 1e-8f);
    float inv = 1.f / s2;
#pragma unroll
    for (int e = 0; e < E_NUM; e++) rw[(size_t)bt * E_NUM + e] = w[e] * inv;
  }
}

// ---------------- x f32 -> bf16 ----------------
__global__ __launch_bounds__(256) void cvt_x_kernel(
    const float* __restrict__ x, short* __restrict__ xb)
{
  const size_t base = ((size_t)blockIdx.x * 256 + threadIdx.x) * 8;
  f32x4 v0 = *(const f32x4*)(x + base);
  f32x4 v1 = *(const f32x4*)(x + base + 4);
  short8 p;
#pragma unroll
  for (int j = 0; j < 4; j++) { p[j] = f2bf(v0[j]); p[4 + j] = f2bf(v1[j]); }
  *(short8*)(xb + base) = p;
}

// ------------- transpose + f32->bf16 -------------
// which 0:Wg 1:Wu -> B' rows np = (col>>5)*64 + which*32 + (col&31)  (32-col pairs)
// which 2:Wd -> WdT[n][e*2048+k], stride nexp*2048.
__global__ __launch_bounds__(256) void transpose_cvt_kernel(
    const float* __restrict__ sg, const float* __restrict__ su, const float* __restrict__ sd,
    short* __restrict__ dgu, short* __restrict__ dd, int nexp)
{
  const int which = blockIdx.z / nexp, e = blockIdx.z % nexp;
  __shared__ float t[32][33];
  const int tx = threadIdx.x, ty = threadIdx.y;
  const int x0 = blockIdx.x * 32, y0 = blockIdx.y * 32;
  const float* s = (which == 0 ? sg : which == 1 ? su : sd) + (size_t)e * MAT_ELEMS;
#pragma unroll
  for (int i = ty; i < 32; i += 8) t[i][tx] = s[(size_t)(y0 + i) * 2048 + x0 + tx];
  __syncthreads();
  if (which < 2) {
    short* d = dgu + (size_t)e * (2 * MAT_ELEMS);
#pragma unroll
    for (int i = ty; i < 32; i += 8) {
      const int col = x0 + i;
      const int np = ((col >> 5) * 64) + which * 32 + (col & 31);
      d[(size_t)np * 2048 + y0 + tx] = f2bf(t[tx][i]);
    }
  } else {
#pragma unroll
    for (int i = ty; i < 32; i += 8)
      dd[(size_t)(x0 + i) * ((size_t)nexp * 2048) + (size_t)e * 2048 + y0 + tx] = f2bf(t[tx][i]);
  }
}

// ================= 256x256 GEMM core, BK=64, 8 waves (2M x 4N), 8-phase =================
// LDS: As/Bs each [2 buf][2 half][128 rows][64 shorts] = 64KB each.
// Swizzle: physical 16B-chunk = logical ^ (row&7); inverse applied on global src.
// Per iter = 2 K-tiles (K=128). vmcnt(4) + barrier only at phases 4 and 8.
__device__ __forceinline__ void gemm_core8(
    const short* __restrict__ Ab, const short* __restrict__ Bb,
    const int ld, const int T,   // T = K/64 tiles, even
    short* As, short* Bs, f32x4 (&acc)[8][4])
{
  const int tid = threadIdx.x;
  const int w = tid >> 6, lane = tid & 63;
  const int wm = w >> 2, wn = w & 3;
  const int r = lane & 15, g4 = lane >> 4;
  const int l3 = lane >> 3, l7 = lane & 7;

  // staging: per-thread global src offset (shot0 of a half-tile); shot1 += 8*ld
  const size_t sSrc = (size_t)(w * 16 + l3) * ld + (size_t)((l7 ^ l3) * 8);
  const int wdst = w * 1024;   // shorts, wave-uniform; shot1 += 512

  // fragment read addresses (bytes)
  const unsigned aB = LDS_OFF(As), bB = LDS_OFF(Bs);
  unsigned aro[2][4], bro[2][2], csb[2];
#pragma unroll
  for (int mh = 0; mh < 2; mh++)
#pragma unroll
    for (int mq = 0; mq < 4; mq++)
      aro[mh][mq] = aB + (unsigned)(wm * 16384 + (mh * 64 + mq * 16 + r) * 128);
#pragma unroll
  for (int nh = 0; nh < 2; nh++)
#pragma unroll
    for (int nq = 0; nq < 2; nq++) {
      const int row = wn * 64 + nh * 32 + nq * 16 + r;
      bro[nh][nq] = bB + (unsigned)((row >> 7) * 16384 + (row & 127) * 128);
    }
#pragma unroll
  for (int kk = 0; kk < 2; kk++)
    csb[kk] = (unsigned)((((kk * 4 + g4) ^ (r & 7)) * 16));

#pragma unroll
  for (int i = 0; i < 8; i++)
#pragma unroll
    for (int jn = 0; jn < 4; jn++) acc[i][jn] = (f32x4){0.f, 0.f, 0.f, 0.f};

#define STG(MAT_LDS, MAT_G, tt, hh) do { \
  const short* gsrc_ = (MAT_G) + (size_t)(hh) * 128 * ld + (size_t)(tt) * 64 + sSrc; \
  short* ldst_ = (MAT_LDS) + ((tt) & 1) * 16384 + (hh) * 8192 + wdst; \
  GLOAD_LDS(gsrc_, ldst_); \
  GLOAD_LDS(gsrc_ + (size_t)8 * ld, ldst_ + 512); \
} while (0)

#define RD_A(mh, b32) do { \
  _Pragma("unroll") \
  for (int mq = 0; mq < 4; mq++) \
    _Pragma("unroll") \
    for (int kk = 0; kk < 2; kk++) \
      DS_READ_B128(Ar[mq * 2 + kk], aro[mh][mq] + (b32) + csb[kk]); \
} while (0)

#define RD_B(nh, DST, b32) do { \
  _Pragma("unroll") \
  for (int nq = 0; nq < 2; nq++) \
    _Pragma("unroll") \
    for (int kk = 0; kk < 2; kk++) \
      DS_READ_B128(DST[nq * 2 + kk], bro[nh][nq] + (b32) + csb[kk]); \
} while (0)

#define MM(BV, mh, nh) do { \
  __builtin_amdgcn_s_setprio(1); \
  _Pragma("unroll") \
  for (int mq = 0; mq < 4; mq++) \
    _Pragma("unroll") \
    for (int nq = 0; nq < 2; nq++) \
      _Pragma("unroll") \
      for (int kk = 0; kk < 2; kk++) \
        acc[(mh) * 4 + mq][(nh) * 2 + nq] = \
            __builtin_amdgcn_mfma_f32_16x16x32_bf16( \
                __builtin_bit_cast(bf16x8, Ar[mq * 2 + kk]), \
                __builtin_bit_cast(bf16x8, BV[nq * 2 + kk]), \
                acc[(mh) * 4 + mq][(nh) * 2 + nq], 0, 0, 0); \
  __builtin_amdgcn_s_setprio(0); \
} while (0)

  // prologue: stage 0·Bh0, 0·Bh1, 0·Ah0, 0·Ah1, 1·Bh0, 1·Bh1 (12 loads)
  STG(Bs, Bb, 0, 0); STG(Bs, Bb, 0, 1);
  STG(As, Ab, 0, 0); STG(As, Ab, 0, 1);
  STG(Bs, Bb, 1, 0); STG(Bs, Bb, 1, 1);
  VMC(4);            // tile 0 fully resident
  BAR();

  short8 Ar[8], B0[4], B1[4];

  for (int t = 0; t < T; t += 2) {
    const int t1 = t + 1;
    const int t2 = (t + 2 < T) ? t + 2 : 0;   // wrap: harmless re-stage
    const int t3 = (t + 3 < T) ? t + 3 : 1;
    // ---- P1: A(mh0)+B(nh0) of tile t (buf0) ; stage (t1)Ah0 ----
    RD_A(0, 0u); RD_B(0, B0, 0u);
    STG(As, Ab, t1, 0);
    BAR(); LGKM0(); MM(B0, 0, 0); BAR();
    // ---- P2: B(nh1) ; stage (t1)Ah1 ----
    RD_B(1, B1, 0u);
    STG(As, Ab, t1, 1);
    BAR(); LGKM0(); MM(B1, 0, 1); BAR();
    // ---- P3: A(mh1) ; stage (t2)Bh0 ----
    RD_A(1, 0u);
    STG(Bs, Bb, t2, 0);
    BAR(); LGKM0(); MM(B0, 1, 0); BAR();
    // ---- P4: stage (t2)Bh1 ; MFMA ; vmcnt(4) gate for tile t+1 ----
    STG(Bs, Bb, t2, 1);
    BAR(); MM(B1, 1, 1);
    VMC(4);
    BAR();
    // ---- P5: A(mh0)+B(nh0) of tile t+1 (buf1) ; stage (t2)Ah0 ----
    RD_A(0, 32768u); RD_B(0, B0, 32768u);
    STG(As, Ab, t2, 0);
    BAR(); LGKM0(); MM(B0, 0, 0); BAR();
    // ---- P6: B(nh1) ; stage (t2)Ah1 ----
    RD_B(1, B1, 32768u);
    STG(As, Ab, t2, 1);
    BAR(); LGKM0(); MM(B1, 0, 1); BAR();
    // ---- P7: A(mh1) ; stage (t3)Bh0 ----
    RD_A(1, 32768u);
    STG(Bs, Bb, t3, 0);
    BAR(); LGKM0(); MM(B0, 1, 0); BAR();
    // ---- P8: stage (t3)Bh1 ; MFMA ; vmcnt(4) gate for tile t+2 ----
    STG(Bs, Bb, t3, 1);
    BAR(); MM(B1, 1, 1);
    VMC(4);
    BAR();
  }
  VMC(0);
#undef STG
#undef RD_A
#undef RD_B
#undef MM
  __builtin_amdgcn_sched_barrier(0);
  asm volatile("s_nop 7\n\ts_nop 7" ::: "memory");
}

// ---------------- fused gate+up kernel ----------------
// B' per expert: 4096 rows (32-col interleave). nh=0 gate, nh=1 up.
template<int BATCHED>
__global__ __launch_bounds__(512, 1) void fused_gu_kernel(
    const short* __restrict__ xb, const short* __restrict__ Bgu,
    short* __restrict__ h, const float* __restrict__ rw, int e_param)
{
  __shared__ short As_[32768];
  __shared__ short Bs_[32768];
  int bx, by, e;
  const short* Bp;
  long hstride, hcol0;
  if (BATCHED) {
    const int swz = (blockIdx.x & 7) * 256 + (blockIdx.x >> 3);
    e = swz >> 8;
    const int rem = swz & 255;
    by = rem >> 4; bx = rem & 15;
    Bp = Bgu + (size_t)e * (2 * MAT_ELEMS);
    hstride = 16384; hcol0 = (long)e * 2048;
  } else {
    const int swz = (blockIdx.x & 7) * 32 + (blockIdx.x >> 3);
    e = e_param;
    by = swz >> 4; bx = swz & 15;
    Bp = Bgu;
    hstride = 2048; hcol0 = 0;
  }
  const int m0 = by * 256, n0 = bx * 256;

  f32x4 acc[8][4];
  gemm_core8(xb + (size_t)m0 * 2048, Bp + (size_t)n0 * 2048, 2048, 32, As_, Bs_, acc);

  const int tid = threadIdx.x;
  const int w = tid >> 6, lane = tid & 63;
  const int wm = w >> 2, wn = w & 3;
  const int r = lane & 15, g4 = lane >> 4;
#pragma unroll
  for (int mi = 0; mi < 8; mi++) {
#pragma unroll
    for (int j = 0; j < 4; j++) {
      const int row = m0 + wm * 128 + (mi >> 2) * 64 + (mi & 3) * 16 + g4 * 4 + j;
      const float wt = rw[(size_t)row * 8 + e];
#pragma unroll
      for (int nq = 0; nq < 2; nq++) {
        const float g = acc[mi][nq][j];        // nh=0 (gate)
        const float u = acc[mi][2 + nq][j];    // nh=1 (up)
        const float hv = (g / (1.f + __expf(-g))) * u * wt;
        const long c = (long)(bx * 4 + wn) * 32 + nq * 16 + r;
        h[(size_t)row * hstride + hcol0 + c] = f2bf(hv);
      }
    }
  }
}

// ---------------- down kernel (split-K=2, f32 partials) ----------------
template<int BATCHED>
__global__ __launch_bounds__(512, 1) void down_kernel(
    const short* __restrict__ h, const short* __restrict__ WdT,
    float* __restrict__ part)
{
  __shared__ short As_[32768];
  __shared__ short Bs_[32768];
  const int swz = (blockIdx.x & 7) * 32 + (blockIdx.x >> 3);
  const int z = swz >> 7;
  const int rem = swz & 127;
  const int by = rem >> 3, bx = rem & 7;
  const int m0 = by * 256, n0 = bx * 256;
  const int ld = BATCHED ? 16384 : 2048;
  const int kz = BATCHED ? 8192 : 1024;
  const int T = kz / 64;

  f32x4 acc[8][4];
  gemm_core8(h + (size_t)m0 * ld + (size_t)z * kz,
             WdT + (size_t)n0 * ld + (size_t)z * kz, ld, T, As_, Bs_, acc);

  float* pz = part + (size_t)z * BT_NUM * 2048;
  const int tid = threadIdx.x;
  const int w = tid >> 6, lane = tid & 63;
  const int wm = w >> 2, wn = w & 3;
  const int r = lane & 15, g4 = lane >> 4;
#pragma unroll
  for (int mi = 0; mi < 8; mi++) {
#pragma unroll
    for (int ni = 0; ni < 4; ni++) {
      const int col = n0 + wn * 64 + (ni >> 1) * 32 + (ni & 1) * 16 + r;
#pragma unroll
      for (int j = 0; j < 4; j++) {
        const int row = m0 + wm * 128 + (mi >> 2) * 64 + (mi & 3) * 16 + g4 * 4 + j;
        pz[(size_t)row * 2048 + col] = acc[mi][ni][j];
      }
    }
  }
}

// ---------------- add partials ----------------
__global__ __launch_bounds__(256) void add2_kernel(
    const float* __restrict__ p0, const float* __restrict__ p1,
    float* __restrict__ out, int accum)
{
  const size_t i = ((size_t)blockIdx.x * 256 + threadIdx.x) * 4;
  f32x4 v = *(const f32x4*)(p0 + i) + *(const f32x4*)(p1 + i);
  if (accum) v += *(const f32x4*)(out + i);
  *(f32x4*)(out + i) = v;
}

extern "C" void kernel_launch(void* const* d_in, const int* in_sizes, int n_in,
                              void* d_out, int out_size, void* d_ws, size_t ws_size,
                              hipStream_t stream)
{
  const float* x  = (const float*)d_in[0];
  const float* Wg = (const float*)d_in[1];
  const float* Wu = (const float*)d_in[2];
  const float* Wd = (const float*)d_in[3];
  const float* Wr = (const float*)d_in[4];
  const float* tp = (const float*)d_in[5];
  float* out = (float*)d_out;

  char* ws = (char*)d_ws;
  const size_t SZ_RW = (size_t)BT_NUM * 8 * 4;
  const size_t SZ_XB = (size_t)BT_NUM * 2048 * 2;
  const size_t SZ_BGU_E = 2 * MAT_ELEMS * 2;

  const size_t FULL = SZ_RW + SZ_XB + 8 * SZ_BGU_E
                    + (size_t)2048 * 16384 * 2
                    + (size_t)BT_NUM * 16384 * 2;

  float* rw = (float*)ws;
  router_kernel<<<BT_NUM, 256, 0, stream>>>(x, Wr, tp, rw);

  if (ws_size >= FULL) {
    size_t off = SZ_RW;
    short* xb  = (short*)(ws + off); off += SZ_XB;
    short* Bgu = (short*)(ws + off); off += 8 * SZ_BGU_E;
    short* WdT = (short*)(ws + off); off += (size_t)2048 * 16384 * 2;
    short* h   = (short*)(ws + off);
    float* part = (float*)Bgu;   // reuse B' region after fused_gu

    cvt_x_kernel<<<4096, 256, 0, stream>>>(x, xb);
    transpose_cvt_kernel<<<dim3(64, 64, 24), dim3(32, 8), 0, stream>>>(
        Wg, Wu, Wd, Bgu, WdT, 8);
    fused_gu_kernel<1><<<2048, 512, 0, stream>>>(xb, Bgu, h, rw, 0);
    down_kernel<1><<<256, 512, 0, stream>>>(h, WdT, part);
    add2_kernel<<<8192, 256, 0, stream>>>(part, part + (size_t)BT_NUM * 2048, out, 0);
  } else {
    size_t off = SZ_RW;
    short* xb  = (short*)(ws + off); off += SZ_XB;
    short* Bgu = (short*)(ws + off); off += SZ_BGU_E;
    short* WdT = (short*)(ws + off); off += MAT_ELEMS * 2;
    short* h   = (short*)(ws + off); off += (size_t)BT_NUM * 2048 * 2;
    float* part = (float*)(ws + off);

    cvt_x_kernel<<<4096, 256, 0, stream>>>(x, xb);
    for (int e = 0; e < 8; e++) {
      transpose_cvt_kernel<<<dim3(64, 64, 3), dim3(32, 8), 0, stream>>>(
          Wg + (size_t)e * MAT_ELEMS, Wu + (size_t)e * MAT_ELEMS,
          Wd + (size_t)e * MAT_ELEMS, Bgu, WdT, 1);
      fused_gu_kernel<0><<<256, 512, 0, stream>>>(xb, Bgu, h, rw, e);
      down_kernel<0><<<256, 512, 0, stream>>>(h, WdT, part);
      add2_kernel<<<8192, 256, 0, stream>>>(part, part + (size_t)BT_NUM * 2048, out, e > 0);
    }
  }
}

// Round 8
// 807.873 us; speedup vs baseline: 1.1208x; 1.1208x over previous
//
#include <hip/hip_runtime.h>
#include <hip/hip_bf16.h>
#include <math.h>

// GoldenMoE: B=2,T=2048,D=2048,E=8,F=2048.
// Round 8: SPARSE token-gather MoE. Router weights are exactly 0 for ~59% of
// (token,expert) pairs (golden-zone gating) -> per-expert compact token lists,
// gathered A-staging in fused_gu, compact h', per-expert down with atomic
// scatter-add into zeroed out. 8-phase GEMM core kept; MM reordered kk-outer.

#define E_NUM 8
#define BT_NUM 4096
#define MAT_ELEMS ((size_t)2048 * 2048)

typedef short short8 __attribute__((ext_vector_type(8)));
typedef float f32x4 __attribute__((ext_vector_type(4)));
typedef __bf16 bf16x8 __attribute__((ext_vector_type(8)));

__device__ __forceinline__ short f2bf(float f) {
  __hip_bfloat16 h = __float2bfloat16(f);
  return __builtin_bit_cast(short, h);
}

#define GLOAD_LDS(gptr, lptr) \
  __builtin_amdgcn_global_load_lds( \
      (const __attribute__((address_space(1))) unsigned int*)(gptr), \
      (__attribute__((address_space(3))) unsigned int*)(lptr), 16, 0, 0)

#define LDS_OFF(p) ((unsigned)(size_t)(__attribute__((address_space(3))) const short*)(p))

#define DS_READ_B128(d, a) \
  asm volatile("ds_read_b128 %0, %1" : "=v"(d) : "v"(a))

#define BAR() __builtin_amdgcn_s_barrier()
#define LGKM0() do { \
  asm volatile("s_waitcnt lgkmcnt(0)" ::: "memory"); \
  __builtin_amdgcn_sched_barrier(0); \
} while (0)
#define VMC(n) asm volatile("s_waitcnt vmcnt(" #n ")" ::: "memory")

// ---------------- router ----------------
__global__ __launch_bounds__(256) void router_kernel(
    const float* __restrict__ x, const float* __restrict__ Wr,
    const float* __restrict__ temp, float* __restrict__ rw)
{
  const int bt = blockIdx.x;
  const int tid = threadIdx.x;
  const float* xp = x + (size_t)bt * 2048;
  float acc[E_NUM];
#pragma unroll
  for (int e = 0; e < E_NUM; e++) acc[e] = 0.f;
  for (int d = tid; d < 2048; d += 256) {
    float xv = xp[d];
    const float* wr = Wr + (size_t)d * E_NUM;
#pragma unroll
    for (int e = 0; e < E_NUM; e++) acc[e] += xv * wr[e];
  }
#pragma unroll
  for (int e = 0; e < E_NUM; e++) {
    float v = acc[e];
#pragma unroll
    for (int off = 32; off > 0; off >>= 1) v += __shfl_down(v, off, 64);
    acc[e] = v;
  }
  __shared__ float part[4][E_NUM];
  const int wid = tid >> 6, lane = tid & 63;
  if (lane == 0) {
#pragma unroll
    for (int e = 0; e < E_NUM; e++) part[wid][e] = acc[e];
  }
  __syncthreads();
  if (tid == 0) {
    const float t = temp[0];
    float wz[E_NUM], fb[E_NUM];
    float wsum = 0.f;
#pragma unroll
    for (int e = 0; e < E_NUM; e++) {
      float l = part[0][e] + part[1][e] + part[2][e] + part[3][e];
      float ih = 1.f / (1.f + expf(-l / t));
      float ds = fabsf(ih - 0.36787944117144233f);
      float in_zone = (ih >= 0.21231792754821915f && ih <= 0.5f) ? 1.f : 0.f;
      wz[e] = expf(-ds / 0.1f) * in_zone;
      wsum += wz[e];
      fb[e] = expf(-ds / 0.3f);
    }
    float w[E_NUM];
    if (wsum < 1e-8f) {
      int i1 = 0;
#pragma unroll
      for (int e = 1; e < E_NUM; e++) if (fb[e] > fb[i1]) i1 = e;
      int i2 = -1;
#pragma unroll
      for (int e = 0; e < E_NUM; e++) if (e != i1 && (i2 < 0 || fb[e] > fb[i2])) i2 = e;
      float s = fmaxf(fb[i1] + fb[i2], 1e-8f);
#pragma unroll
      for (int e = 0; e < E_NUM; e++) w[e] = (e == i1 || e == i2) ? fb[e] / s : 0.f;
    } else {
#pragma unroll
      for (int e = 0; e < E_NUM; e++) w[e] = wz[e];
    }
    float s2 = 0.f;
#pragma unroll
    for (int e = 0; e < E_NUM; e++) s2 += w[e];
    s2 = fmaxf(s2, 1e-8f);
    float inv = 1.f / s2;
#pragma unroll
    for (int e = 0; e < E_NUM; e++) rw[(size_t)bt * E_NUM + e] = w[e] * inv;
  }
}

// ---------------- sparse bookkeeping ----------------
__global__ void init_cnt_kernel(int* __restrict__ cnt) {
  if (threadIdx.x < E_NUM) cnt[threadIdx.x] = 0;
}

__global__ __launch_bounds__(256) void build_idx_kernel(
    const float* __restrict__ rw, int* __restrict__ cnt,
    unsigned short* __restrict__ idx)
{
  const int t = blockIdx.x * 256 + threadIdx.x;
  const float* w = rw + (size_t)t * E_NUM;
#pragma unroll
  for (int e = 0; e < E_NUM; e++) {
    if (w[e] != 0.f) {
      int p = atomicAdd(&cnt[e], 1);
      idx[(size_t)e * BT_NUM + p] = (unsigned short)t;
    }
  }
}

__global__ __launch_bounds__(256) void zero_out_kernel(float* __restrict__ out) {
  const size_t i = ((size_t)blockIdx.x * 256 + threadIdx.x) * 4;
  *(f32x4*)(out + i) = (f32x4){0.f, 0.f, 0.f, 0.f};
}

// ---------------- x f32 -> bf16 ----------------
__global__ __launch_bounds__(256) void cvt_x_kernel(
    const float* __restrict__ x, short* __restrict__ xb)
{
  const size_t base = ((size_t)blockIdx.x * 256 + threadIdx.x) * 8;
  f32x4 v0 = *(const f32x4*)(x + base);
  f32x4 v1 = *(const f32x4*)(x + base + 4);
  short8 p;
#pragma unroll
  for (int j = 0; j < 4; j++) { p[j] = f2bf(v0[j]); p[4 + j] = f2bf(v1[j]); }
  *(short8*)(xb + base) = p;
}

// ------------- transpose + f32->bf16 -------------
// which 0:Wg 1:Wu -> B' rows np=(col>>5)*64+which*32+(col&31), per-expert block.
// which 2:Wd -> per-expert WdT[e][n][k].
__global__ __launch_bounds__(256) void transpose_cvt_kernel(
    const float* __restrict__ sg, const float* __restrict__ su, const float* __restrict__ sd,
    short* __restrict__ dgu, short* __restrict__ dd, int nexp)
{
  const int which = blockIdx.z / nexp, e = blockIdx.z % nexp;
  __shared__ float t[32][33];
  const int tx = threadIdx.x, ty = threadIdx.y;
  const int x0 = blockIdx.x * 32, y0 = blockIdx.y * 32;
  const float* s = (which == 0 ? sg : which == 1 ? su : sd) + (size_t)e * MAT_ELEMS;
#pragma unroll
  for (int i = ty; i < 32; i += 8) t[i][tx] = s[(size_t)(y0 + i) * 2048 + x0 + tx];
  __syncthreads();
  if (which < 2) {
    short* d = dgu + (size_t)e * (2 * MAT_ELEMS);
#pragma unroll
    for (int i = ty; i < 32; i += 8) {
      const int col = x0 + i;
      const int np = ((col >> 5) * 64) + which * 32 + (col & 31);
      d[(size_t)np * 2048 + y0 + tx] = f2bf(t[tx][i]);
    }
  } else {
#pragma unroll
    for (int i = ty; i < 32; i += 8)
      dd[(size_t)e * MAT_ELEMS + (size_t)(x0 + i) * 2048 + y0 + tx] = f2bf(t[tx][i]);
  }
}

// ================= 256x256 GEMM core, BK=64, 8 waves, 8-phase =================
// A comes from 4 pre-swizzled per-thread row pointers (gather-capable).
// B linear [rows][2048]. T = K/64 tiles (even). MM is kk-outer (no dep bubbles).
__device__ __forceinline__ void gemm_core8(
    const short* a00, const short* a01, const short* a10, const short* a11,
    const short* __restrict__ Bb, const int T,
    short* As, short* Bs, f32x4 (&acc)[8][4])
{
  const int tid = threadIdx.x;
  const int w = tid >> 6, lane = tid & 63;
  const int wm = w >> 2, wn = w & 3;
  const int r = lane & 15, g4 = lane >> 4;
  const int l3 = lane >> 3, l7 = lane & 7;

  const size_t bOff = (size_t)(w * 16 + l3) * 2048 + (size_t)((l7 ^ l3) * 8);
  const int wdst = w * 1024;

  const unsigned aB = LDS_OFF(As), bB = LDS_OFF(Bs);
  unsigned aro[2][4], bro[2][2], csb[2];
#pragma unroll
  for (int mh = 0; mh < 2; mh++)
#pragma unroll
    for (int mq = 0; mq < 4; mq++)
      aro[mh][mq] = aB + (unsigned)(wm * 16384 + (mh * 64 + mq * 16 + r) * 128);
#pragma unroll
  for (int nh = 0; nh < 2; nh++)
#pragma unroll
    for (int nq = 0; nq < 2; nq++) {
      const int row = wn * 64 + nh * 32 + nq * 16 + r;
      bro[nh][nq] = bB + (unsigned)((row >> 7) * 16384 + (row & 127) * 128);
    }
#pragma unroll
  for (int kk = 0; kk < 2; kk++)
    csb[kk] = (unsigned)((((kk * 4 + g4) ^ (r & 7)) * 16));

#pragma unroll
  for (int i = 0; i < 8; i++)
#pragma unroll
    for (int jn = 0; jn < 4; jn++) acc[i][jn] = (f32x4){0.f, 0.f, 0.f, 0.f};

#define STG_A(tt, hh) do { \
  const short* g0_ = ((hh) ? a10 : a00) + (tt) * 64; \
  const short* g1_ = ((hh) ? a11 : a01) + (tt) * 64; \
  short* ld_ = As + ((tt) & 1) * 16384 + (hh) * 8192 + wdst; \
  GLOAD_LDS(g0_, ld_); GLOAD_LDS(g1_, ld_ + 512); \
} while (0)

#define STG_B(tt, hh) do { \
  const short* g_ = Bb + bOff + (size_t)(hh) * 128 * 2048 + (tt) * 64; \
  short* ld_ = Bs + ((tt) & 1) * 16384 + (hh) * 8192 + wdst; \
  GLOAD_LDS(g_, ld_); GLOAD_LDS(g_ + (size_t)8 * 2048, ld_ + 512); \
} while (0)

#define RD_A(mh, b32) do { \
  _Pragma("unroll") \
  for (int mq = 0; mq < 4; mq++) \
    _Pragma("unroll") \
    for (int kk = 0; kk < 2; kk++) \
      DS_READ_B128(Ar[mq * 2 + kk], aro[mh][mq] + (b32) + csb[kk]); \
} while (0)

#define RD_B(nh, DST, b32) do { \
  _Pragma("unroll") \
  for (int nq = 0; nq < 2; nq++) \
    _Pragma("unroll") \
    for (int kk = 0; kk < 2; kk++) \
      DS_READ_B128(DST[nq * 2 + kk], bro[nh][nq] + (b32) + csb[kk]); \
} while (0)

#define MM(BV, mh, nh) do { \
  __builtin_amdgcn_s_setprio(1); \
  _Pragma("unroll") \
  for (int kk = 0; kk < 2; kk++) \
    _Pragma("unroll") \
    for (int mq = 0; mq < 4; mq++) \
      _Pragma("unroll") \
      for (int nq = 0; nq < 2; nq++) \
        acc[(mh) * 4 + mq][(nh) * 2 + nq] = \
            __builtin_amdgcn_mfma_f32_16x16x32_bf16( \
                __builtin_bit_cast(bf16x8, Ar[mq * 2 + kk]), \
                __builtin_bit_cast(bf16x8, BV[nq * 2 + kk]), \
                acc[(mh) * 4 + mq][(nh) * 2 + nq], 0, 0, 0); \
  __builtin_amdgcn_s_setprio(0); \
} while (0)

  // prologue: tile0 B,A then tile1 B (12 loads); vmcnt(4) -> tile0 resident
  STG_B(0, 0); STG_B(0, 1);
  STG_A(0, 0); STG_A(0, 1);
  STG_B(1, 0); STG_B(1, 1);
  VMC(4);
  BAR();

  short8 Ar[8], B0[4], B1[4];

  for (int t = 0; t < T; t += 2) {
    const int t1 = t + 1;
    const int t2 = (t + 2 < T) ? t + 2 : 0;   // wrap: harmless re-stage
    const int t3 = (t + 3 < T) ? t + 3 : 1;
    // P1
    RD_A(0, 0u); RD_B(0, B0, 0u);
    STG_A(t1, 0);
    BAR(); LGKM0(); MM(B0, 0, 0); BAR();
    // P2
    RD_B(1, B1, 0u);
    STG_A(t1, 1);
    BAR(); LGKM0(); MM(B1, 0, 1); BAR();
    // P3
    RD_A(1, 0u);
    STG_B(t2, 0);
    BAR(); LGKM0(); MM(B0, 1, 0); BAR();
    // P4
    STG_B(t2, 1);
    BAR(); MM(B1, 1, 1);
    VMC(4);
    BAR();
    // P5
    RD_A(0, 32768u); RD_B(0, B0, 32768u);
    STG_A(t2, 0);
    BAR(); LGKM0(); MM(B0, 0, 0); BAR();
    // P6
    RD_B(1, B1, 32768u);
    STG_A(t2, 1);
    BAR(); LGKM0(); MM(B1, 0, 1); BAR();
    // P7
    RD_A(1, 32768u);
    STG_B(t3, 0);
    BAR(); LGKM0(); MM(B0, 1, 0); BAR();
    // P8
    STG_B(t3, 1);
    BAR(); MM(B1, 1, 1);
    VMC(4);
    BAR();
  }
  VMC(0);
#undef STG_A
#undef STG_B
#undef RD_A
#undef RD_B
#undef MM
  __builtin_amdgcn_sched_barrier(0);
  asm volatile("s_nop 7\n\ts_nop 7" ::: "memory");
}

// ---------------- fused gate+up (gathered A, compact h') ----------------
// grid (16 bx, 16 by, NE); block 512. Early-exit if tile beyond cnt[e].
__global__ __launch_bounds__(512, 1) void fused_gu_kernel(
    const short* __restrict__ xb, const short* __restrict__ Bgu,
    short* __restrict__ h, const float* __restrict__ rw,
    const unsigned short* __restrict__ idx, const int* __restrict__ cnt,
    int e_base)
{
  const int ez = blockIdx.z, e = e_base + ez;
  const int cntE = cnt[e];
  const int by = blockIdx.y, bx = blockIdx.x;
  const int m0 = by * 256;
  if (m0 >= cntE) return;
  const int n0 = bx * 256;
  const unsigned short* idxe = idx + (size_t)e * BT_NUM;

  __shared__ short As_[32768];
  __shared__ short Bs_[32768];

  const int tid = threadIdx.x;
  const int w = tid >> 6, lane = tid & 63;
  const int l3 = lane >> 3, l7 = lane & 7;
  const int r0 = m0 + w * 16 + l3;
  const int cm = cntE - 1;
  const size_t swz = (size_t)((l7 ^ l3) * 8);
  const short* a00 = xb + (size_t)idxe[min(r0, cm)] * 2048 + swz;
  const short* a01 = xb + (size_t)idxe[min(r0 + 8, cm)] * 2048 + swz;
  const short* a10 = xb + (size_t)idxe[min(r0 + 128, cm)] * 2048 + swz;
  const short* a11 = xb + (size_t)idxe[min(r0 + 136, cm)] * 2048 + swz;

  f32x4 acc[8][4];
  gemm_core8(a00, a01, a10, a11,
             Bgu + (size_t)ez * (2 * MAT_ELEMS) + (size_t)n0 * 2048,
             32, As_, Bs_, acc);

  short* he = h + (size_t)ez * BT_NUM * 2048;
  const int wm = w >> 2, wn = w & 3;
  const int rr = lane & 15, g4 = lane >> 4;
#pragma unroll
  for (int mi = 0; mi < 8; mi++) {
#pragma unroll
    for (int j = 0; j < 4; j++) {
      const int row = m0 + wm * 128 + (mi >> 2) * 64 + (mi & 3) * 16 + g4 * 4 + j;
      const int tok = idxe[min(row, cm)];
      const float wt = rw[(size_t)tok * 8 + e];
#pragma unroll
      for (int nq = 0; nq < 2; nq++) {
        const float g = acc[mi][nq][j];        // nh=0 (gate)
        const float u = acc[mi][2 + nq][j];    // nh=1 (up)
        const float hv = (g / (1.f + __expf(-g))) * u * wt;
        const int c = (bx * 4 + wn) * 32 + nq * 16 + rr;
        he[(size_t)row * 2048 + c] = f2bf(hv);
      }
    }
  }
}

// ---------------- down (compact A, atomic scatter-add) ----------------
// grid (8 bx, 16 by, NE); block 512.
__global__ __launch_bounds__(512, 1) void down_kernel(
    const short* __restrict__ h, const short* __restrict__ WdT,
    float* __restrict__ out,
    const unsigned short* __restrict__ idx, const int* __restrict__ cnt,
    int e_base)
{
  const int ez = blockIdx.z, e = e_base + ez;
  const int cntE = cnt[e];
  const int by = blockIdx.y, bx = blockIdx.x;
  const int m0 = by * 256;
  if (m0 >= cntE) return;
  const int n0 = bx * 256;
  const unsigned short* idxe = idx + (size_t)e * BT_NUM;

  __shared__ short As_[32768];
  __shared__ short Bs_[32768];

  const int tid = threadIdx.x;
  const int w = tid >> 6, lane = tid & 63;
  const int l3 = lane >> 3, l7 = lane & 7;
  const size_t swz = (size_t)((l7 ^ l3) * 8);
  const short* he = h + (size_t)ez * BT_NUM * 2048;
  const short* a00 = he + (size_t)(m0 + w * 16 + l3) * 2048 + swz;
  const short* a01 = a00 + (size_t)8 * 2048;
  const short* a10 = a00 + (size_t)128 * 2048;
  const short* a11 = a00 + (size_t)136 * 2048;

  f32x4 acc[8][4];
  gemm_core8(a00, a01, a10, a11,
             WdT + (size_t)ez * MAT_ELEMS + (size_t)n0 * 2048,
             32, As_, Bs_, acc);

  const int wm = w >> 2, wn = w & 3;
  const int rr = lane & 15, g4 = lane >> 4;
#pragma unroll
  for (int mi = 0; mi < 8; mi++) {
#pragma unroll
    for (int ni = 0; ni < 4; ni++) {
      const int col = n0 + wn * 64 + (ni >> 1) * 32 + (ni & 1) * 16 + rr;
#pragma unroll
      for (int j = 0; j < 4; j++) {
        const int row = m0 + wm * 128 + (mi >> 2) * 64 + (mi & 3) * 16 + g4 * 4 + j;
        if (row < cntE) {
          const int tok = idxe[row];
          unsafeAtomicAdd(&out[(size_t)tok * 2048 + col], acc[mi][ni][j]);
        }
      }
    }
  }
}

extern "C" void kernel_launch(void* const* d_in, const int* in_sizes, int n_in,
                              void* d_out, int out_size, void* d_ws, size_t ws_size,
                              hipStream_t stream)
{
  const float* x  = (const float*)d_in[0];
  const float* Wg = (const float*)d_in[1];
  const float* Wu = (const float*)d_in[2];
  const float* Wd = (const float*)d_in[3];
  const float* Wr = (const float*)d_in[4];
  const float* tp = (const float*)d_in[5];
  float* out = (float*)d_out;

  char* ws = (char*)d_ws;
  const size_t SZ_RW  = 131072;                       // [4096][8] f32
  const size_t SZ_CNT = 4096;                         // int[8] (padded)
  const size_t SZ_IDX = (size_t)E_NUM * BT_NUM * 2;   // ushort [8][4096]
  const size_t SZ_XB  = (size_t)BT_NUM * 2048 * 2;    // 16 MiB
  const size_t SZ_BGU_E = 2 * MAT_ELEMS * 2;          // 16 MiB
  const size_t SZ_WDT_E = MAT_ELEMS * 2;              // 8 MiB
  const size_t SZ_H_E = (size_t)BT_NUM * 2048 * 2;    // 16 MiB

  const size_t FULL = SZ_RW + SZ_CNT + SZ_IDX + SZ_XB
                    + 8 * SZ_BGU_E + 8 * SZ_WDT_E + 8 * SZ_H_E;

  float* rw = (float*)ws;
  int* cnt = (int*)(ws + SZ_RW);
  unsigned short* idx = (unsigned short*)(ws + SZ_RW + SZ_CNT);
  short* xb = (short*)(ws + SZ_RW + SZ_CNT + SZ_IDX);
  char* rest = ws + SZ_RW + SZ_CNT + SZ_IDX + SZ_XB;

  router_kernel<<<BT_NUM, 256, 0, stream>>>(x, Wr, tp, rw);
  init_cnt_kernel<<<1, 64, 0, stream>>>(cnt);
  build_idx_kernel<<<16, 256, 0, stream>>>(rw, cnt, idx);
  cvt_x_kernel<<<4096, 256, 0, stream>>>(x, xb);
  zero_out_kernel<<<8192, 256, 0, stream>>>(out);

  if (ws_size >= FULL) {
    short* Bgu = (short*)rest;
    short* WdT = (short*)(rest + 8 * SZ_BGU_E);
    short* h   = (short*)(rest + 8 * SZ_BGU_E + 8 * SZ_WDT_E);

    transpose_cvt_kernel<<<dim3(64, 64, 24), dim3(32, 8), 0, stream>>>(
        Wg, Wu, Wd, Bgu, WdT, 8);
    fused_gu_kernel<<<dim3(16, 16, 8), 512, 0, stream>>>(
        xb, Bgu, h, rw, idx, cnt, 0);
    down_kernel<<<dim3(8, 16, 8), 512, 0, stream>>>(
        h, WdT, out, idx, cnt, 0);
  } else {
    short* Bgu = (short*)rest;
    short* WdT = (short*)(rest + SZ_BGU_E);
    short* h   = (short*)(rest + SZ_BGU_E + SZ_WDT_E);

    for (int e = 0; e < 8; e++) {
      transpose_cvt_kernel<<<dim3(64, 64, 3), dim3(32, 8), 0, stream>>>(
          Wg + (size_t)e * MAT_ELEMS, Wu + (size_t)e * MAT_ELEMS,
          Wd + (size_t)e * MAT_ELEMS, Bgu, WdT, 1);
      fused_gu_kernel<<<dim3(16, 16, 1), 512, 0, stream>>>(
          xb, Bgu, h, rw, idx, cnt, e);
      down_kernel<<<dim3(8, 16, 1), 512, 0, stream>>>(
          h, WdT, out, idx, cnt, e);
    }
  }
}

// Round 9
// 674.139 us; speedup vs baseline: 1.3431x; 1.1984x over previous
//
#include <hip/hip_runtime.h>
#include <hip/hip_bf16.h>
#include <math.h>

// GoldenMoE: B=2,T=2048,D=2048,E=8,F=2048.
// Round 9: sparse plumbing overhaul. Packed active-tile lists (no dispatch
// holes), atomic-free down (compact bf16 dout aliasing dead Bgu) + per-token
// gather-combine via inverse map. 8-phase GEMM core unchanged from r8.

#define E_NUM 8
#define BT_NUM 4096
#define MAT_ELEMS ((size_t)2048 * 2048)
#define MAXT 136   // max packed M-tiles: sum ceil(cnt_e/256) <= 128+8

typedef short short8 __attribute__((ext_vector_type(8)));
typedef float f32x4 __attribute__((ext_vector_type(4)));
typedef __bf16 bf16x8 __attribute__((ext_vector_type(8)));

__device__ __forceinline__ short f2bf(float f) {
  __hip_bfloat16 h = __float2bfloat16(f);
  return __builtin_bit_cast(short, h);
}
__device__ __forceinline__ float bf2f(short s) {
  __hip_bfloat16 h = __builtin_bit_cast(__hip_bfloat16, s);
  return __bfloat162float(h);
}

#define GLOAD_LDS(gptr, lptr) \
  __builtin_amdgcn_global_load_lds( \
      (const __attribute__((address_space(1))) unsigned int*)(gptr), \
      (__attribute__((address_space(3))) unsigned int*)(lptr), 16, 0, 0)

#define LDS_OFF(p) ((unsigned)(size_t)(__attribute__((address_space(3))) const short*)(p))

#define DS_READ_B128(d, a) \
  asm volatile("ds_read_b128 %0, %1" : "=v"(d) : "v"(a))

#define BAR() __builtin_amdgcn_s_barrier()
#define LGKM0() do { \
  asm volatile("s_waitcnt lgkmcnt(0)" ::: "memory"); \
  __builtin_amdgcn_sched_barrier(0); \
} while (0)
#define VMC(n) asm volatile("s_waitcnt vmcnt(" #n ")" ::: "memory")

// ---------------- router ----------------
__global__ __launch_bounds__(256) void router_kernel(
    const float* __restrict__ x, const float* __restrict__ Wr,
    const float* __restrict__ temp, float* __restrict__ rw)
{
  const int bt = blockIdx.x;
  const int tid = threadIdx.x;
  const float* xp = x + (size_t)bt * 2048;
  float acc[E_NUM];
#pragma unroll
  for (int e = 0; e < E_NUM; e++) acc[e] = 0.f;
  for (int d = tid; d < 2048; d += 256) {
    float xv = xp[d];
    const float* wr = Wr + (size_t)d * E_NUM;
#pragma unroll
    for (int e = 0; e < E_NUM; e++) acc[e] += xv * wr[e];
  }
#pragma unroll
  for (int e = 0; e < E_NUM; e++) {
    float v = acc[e];
#pragma unroll
    for (int off = 32; off > 0; off >>= 1) v += __shfl_down(v, off, 64);
    acc[e] = v;
  }
  __shared__ float part[4][E_NUM];
  const int wid = tid >> 6, lane = tid & 63;
  if (lane == 0) {
#pragma unroll
    for (int e = 0; e < E_NUM; e++) part[wid][e] = acc[e];
  }
  __syncthreads();
  if (tid == 0) {
    const float t = temp[0];
    float wz[E_NUM], fb[E_NUM];
    float wsum = 0.f;
#pragma unroll
    for (int e = 0; e < E_NUM; e++) {
      float l = part[0][e] + part[1][e] + part[2][e] + part[3][e];
      float ih = 1.f / (1.f + expf(-l / t));
      float ds = fabsf(ih - 0.36787944117144233f);
      float in_zone = (ih >= 0.21231792754821915f && ih <= 0.5f) ? 1.f : 0.f;
      wz[e] = expf(-ds / 0.1f) * in_zone;
      wsum += wz[e];
      fb[e] = expf(-ds / 0.3f);
    }
    float w[E_NUM];
    if (wsum < 1e-8f) {
      int i1 = 0;
#pragma unroll
      for (int e = 1; e < E_NUM; e++) if (fb[e] > fb[i1]) i1 = e;
      int i2 = -1;
#pragma unroll
      for (int e = 0; e < E_NUM; e++) if (e != i1 && (i2 < 0 || fb[e] > fb[i2])) i2 = e;
      float s = fmaxf(fb[i1] + fb[i2], 1e-8f);
#pragma unroll
      for (int e = 0; e < E_NUM; e++) w[e] = (e == i1 || e == i2) ? fb[e] / s : 0.f;
    } else {
#pragma unroll
      for (int e = 0; e < E_NUM; e++) w[e] = wz[e];
    }
    float s2 = 0.f;
#pragma unroll
    for (int e = 0; e < E_NUM; e++) s2 += w[e];
    s2 = fmaxf(s2, 1e-8f);
    float inv = 1.f / s2;
#pragma unroll
    for (int e = 0; e < E_NUM; e++) rw[(size_t)bt * E_NUM + e] = w[e] * inv;
  }
}

// ---------------- sparse bookkeeping ----------------
// cnt page layout (ints): [0..7]=cnt, [16]=ntiles, [32..32+MAXT)=tlist
__global__ void init_cnt_kernel(int* __restrict__ cnt) {
  if (threadIdx.x < 32) cnt[threadIdx.x] = 0;
}

__global__ __launch_bounds__(256) void build_idx_kernel(
    const float* __restrict__ rw, int* __restrict__ cnt,
    unsigned short* __restrict__ idx,
    unsigned short* __restrict__ inv, unsigned char* __restrict__ invn)
{
  const int t = blockIdx.x * 256 + threadIdx.x;
  const float* w = rw + (size_t)t * E_NUM;
  int s = 0;
#pragma unroll
  for (int e = 0; e < E_NUM; e++) {
    if (w[e] != 0.f) {
      int p = atomicAdd(&cnt[e], 1);
      idx[(size_t)e * BT_NUM + p] = (unsigned short)t;
      inv[(size_t)t * E_NUM + s] = (unsigned short)((e << 12) | p);
      s++;
    }
  }
  invn[t] = (unsigned char)s;
}

__global__ void pack_tiles_kernel(int* __restrict__ cnt) {
  if (threadIdx.x == 0) {
    int n = 0;
    for (int e = 0; e < E_NUM; e++) {
      const int nt = (cnt[e] + 255) >> 8;
      for (int by = 0; by < nt; by++) cnt[32 + n++] = (e << 8) | by;
    }
    cnt[16] = n;
  }
}

__global__ __launch_bounds__(256) void zero_out_kernel(float* __restrict__ out) {
  const size_t i = ((size_t)blockIdx.x * 256 + threadIdx.x) * 4;
  *(f32x4*)(out + i) = (f32x4){0.f, 0.f, 0.f, 0.f};
}

// ---------------- x f32 -> bf16 ----------------
__global__ __launch_bounds__(256) void cvt_x_kernel(
    const float* __restrict__ x, short* __restrict__ xb)
{
  const size_t base = ((size_t)blockIdx.x * 256 + threadIdx.x) * 8;
  f32x4 v0 = *(const f32x4*)(x + base);
  f32x4 v1 = *(const f32x4*)(x + base + 4);
  short8 p;
#pragma unroll
  for (int j = 0; j < 4; j++) { p[j] = f2bf(v0[j]); p[4 + j] = f2bf(v1[j]); }
  *(short8*)(xb + base) = p;
}

// ------------- transpose + f32->bf16 -------------
__global__ __launch_bounds__(256) void transpose_cvt_kernel(
    const float* __restrict__ sg, const float* __restrict__ su, const float* __restrict__ sd,
    short* __restrict__ dgu, short* __restrict__ dd, int nexp)
{
  const int which = blockIdx.z / nexp, e = blockIdx.z % nexp;
  __shared__ float t[32][33];
  const int tx = threadIdx.x, ty = threadIdx.y;
  const int x0 = blockIdx.x * 32, y0 = blockIdx.y * 32;
  const float* s = (which == 0 ? sg : which == 1 ? su : sd) + (size_t)e * MAT_ELEMS;
#pragma unroll
  for (int i = ty; i < 32; i += 8) t[i][tx] = s[(size_t)(y0 + i) * 2048 + x0 + tx];
  __syncthreads();
  if (which < 2) {
    short* d = dgu + (size_t)e * (2 * MAT_ELEMS);
#pragma unroll
    for (int i = ty; i < 32; i += 8) {
      const int col = x0 + i;
      const int np = ((col >> 5) * 64) + which * 32 + (col & 31);
      d[(size_t)np * 2048 + y0 + tx] = f2bf(t[tx][i]);
    }
  } else {
#pragma unroll
    for (int i = ty; i < 32; i += 8)
      dd[(size_t)e * MAT_ELEMS + (size_t)(x0 + i) * 2048 + y0 + tx] = f2bf(t[tx][i]);
  }
}

// ================= 256x256 GEMM core, BK=64, 8 waves, 8-phase =================
__device__ __forceinline__ void gemm_core8(
    const short* a00, const short* a01, const short* a10, const short* a11,
    const short* __restrict__ Bb, const int T,
    short* As, short* Bs, f32x4 (&acc)[8][4])
{
  const int tid = threadIdx.x;
  const int w = tid >> 6, lane = tid & 63;
  const int wm = w >> 2, wn = w & 3;
  const int r = lane & 15, g4 = lane >> 4;
  const int l3 = lane >> 3, l7 = lane & 7;

  const size_t bOff = (size_t)(w * 16 + l3) * 2048 + (size_t)((l7 ^ l3) * 8);
  const int wdst = w * 1024;

  const unsigned aB = LDS_OFF(As), bB = LDS_OFF(Bs);
  unsigned aro[2][4], bro[2][2], csb[2];
#pragma unroll
  for (int mh = 0; mh < 2; mh++)
#pragma unroll
    for (int mq = 0; mq < 4; mq++)
      aro[mh][mq] = aB + (unsigned)(wm * 16384 + (mh * 64 + mq * 16 + r) * 128);
#pragma unroll
  for (int nh = 0; nh < 2; nh++)
#pragma unroll
    for (int nq = 0; nq < 2; nq++) {
      const int row = wn * 64 + nh * 32 + nq * 16 + r;
      bro[nh][nq] = bB + (unsigned)((row >> 7) * 16384 + (row & 127) * 128);
    }
#pragma unroll
  for (int kk = 0; kk < 2; kk++)
    csb[kk] = (unsigned)((((kk * 4 + g4) ^ (r & 7)) * 16));

#pragma unroll
  for (int i = 0; i < 8; i++)
#pragma unroll
    for (int jn = 0; jn < 4; jn++) acc[i][jn] = (f32x4){0.f, 0.f, 0.f, 0.f};

#define STG_A(tt, hh) do { \
  const short* g0_ = ((hh) ? a10 : a00) + (tt) * 64; \
  const short* g1_ = ((hh) ? a11 : a01) + (tt) * 64; \
  short* ld_ = As + ((tt) & 1) * 16384 + (hh) * 8192 + wdst; \
  GLOAD_LDS(g0_, ld_); GLOAD_LDS(g1_, ld_ + 512); \
} while (0)

#define STG_B(tt, hh) do { \
  const short* g_ = Bb + bOff + (size_t)(hh) * 128 * 2048 + (tt) * 64; \
  short* ld_ = Bs + ((tt) & 1) * 16384 + (hh) * 8192 + wdst; \
  GLOAD_LDS(g_, ld_); GLOAD_LDS(g_ + (size_t)8 * 2048, ld_ + 512); \
} while (0)

#define RD_A(mh, b32) do { \
  _Pragma("unroll") \
  for (int mq = 0; mq < 4; mq++) \
    _Pragma("unroll") \
    for (int kk = 0; kk < 2; kk++) \
      DS_READ_B128(Ar[mq * 2 + kk], aro[mh][mq] + (b32) + csb[kk]); \
} while (0)

#define RD_B(nh, DST, b32) do { \
  _Pragma("unroll") \
  for (int nq = 0; nq < 2; nq++) \
    _Pragma("unroll") \
    for (int kk = 0; kk < 2; kk++) \
      DS_READ_B128(DST[nq * 2 + kk], bro[nh][nq] + (b32) + csb[kk]); \
} while (0)

#define MM(BV, mh, nh) do { \
  __builtin_amdgcn_s_setprio(1); \
  _Pragma("unroll") \
  for (int kk = 0; kk < 2; kk++) \
    _Pragma("unroll") \
    for (int mq = 0; mq < 4; mq++) \
      _Pragma("unroll") \
      for (int nq = 0; nq < 2; nq++) \
        acc[(mh) * 4 + mq][(nh) * 2 + nq] = \
            __builtin_amdgcn_mfma_f32_16x16x32_bf16( \
                __builtin_bit_cast(bf16x8, Ar[mq * 2 + kk]), \
                __builtin_bit_cast(bf16x8, BV[nq * 2 + kk]), \
                acc[(mh) * 4 + mq][(nh) * 2 + nq], 0, 0, 0); \
  __builtin_amdgcn_s_setprio(0); \
} while (0)

  STG_B(0, 0); STG_B(0, 1);
  STG_A(0, 0); STG_A(0, 1);
  STG_B(1, 0); STG_B(1, 1);
  VMC(4);
  BAR();

  short8 Ar[8], B0[4], B1[4];

  for (int t = 0; t < T; t += 2) {
    const int t1 = t + 1;
    const int t2 = (t + 2 < T) ? t + 2 : 0;
    const int t3 = (t + 3 < T) ? t + 3 : 1;
    // P1
    RD_A(0, 0u); RD_B(0, B0, 0u);
    STG_A(t1, 0);
    BAR(); LGKM0(); MM(B0, 0, 0); BAR();
    // P2
    RD_B(1, B1, 0u);
    STG_A(t1, 1);
    BAR(); LGKM0(); MM(B1, 0, 1); BAR();
    // P3
    RD_A(1, 0u);
    STG_B(t2, 0);
    BAR(); LGKM0(); MM(B0, 1, 0); BAR();
    // P4
    STG_B(t2, 1);
    BAR(); MM(B1, 1, 1);
    VMC(4);
    BAR();
    // P5
    RD_A(0, 32768u); RD_B(0, B0, 32768u);
    STG_A(t2, 0);
    BAR(); LGKM0(); MM(B0, 0, 0); BAR();
    // P6
    RD_B(1, B1, 32768u);
    STG_A(t2, 1);
    BAR(); LGKM0(); MM(B1, 0, 1); BAR();
    // P7
    RD_A(1, 32768u);
    STG_B(t3, 0);
    BAR(); LGKM0(); MM(B0, 1, 0); BAR();
    // P8
    STG_B(t3, 1);
    BAR(); MM(B1, 1, 1);
    VMC(4);
    BAR();
  }
  VMC(0);
#undef STG_A
#undef STG_B
#undef RD_A
#undef RD_B
#undef MM
  __builtin_amdgcn_sched_barrier(0);
  asm volatile("s_nop 7\n\ts_nop 7" ::: "memory");
}

// ---------------- fused gate+up (gathered A, compact h') ----------------
// Packed mode (tlist!=null): grid (16, MAXT); else r8 grid (16, 16) per-expert.
__global__ __launch_bounds__(512, 1) void fused_gu_kernel(
    const short* __restrict__ xb, const short* __restrict__ Bgu,
    short* __restrict__ h, const float* __restrict__ rw,
    const unsigned short* __restrict__ idx, const int* __restrict__ cnt,
    int e_param, int packed)
{
  int e, by, eb;
  if (packed) {
    const int nt = cnt[16];
    if ((int)blockIdx.y >= nt) return;
    const int tl = cnt[32 + blockIdx.y];
    e = tl >> 8; by = tl & 255; eb = e;
  } else {
    e = e_param; by = blockIdx.y; eb = 0;
  }
  const int cntE = cnt[e];
  const int m0 = by * 256;
  if (m0 >= cntE) return;
  const int bx = blockIdx.x;
  const int n0 = bx * 256;
  const unsigned short* idxe = idx + (size_t)e * BT_NUM;

  __shared__ short As_[32768];
  __shared__ short Bs_[32768];

  const int tid = threadIdx.x;
  const int w = tid >> 6, lane = tid & 63;
  const int l3 = lane >> 3, l7 = lane & 7;
  const int r0 = m0 + w * 16 + l3;
  const int cm = cntE - 1;
  const size_t swz = (size_t)((l7 ^ l3) * 8);
  const short* a00 = xb + (size_t)idxe[min(r0, cm)] * 2048 + swz;
  const short* a01 = xb + (size_t)idxe[min(r0 + 8, cm)] * 2048 + swz;
  const short* a10 = xb + (size_t)idxe[min(r0 + 128, cm)] * 2048 + swz;
  const short* a11 = xb + (size_t)idxe[min(r0 + 136, cm)] * 2048 + swz;

  f32x4 acc[8][4];
  gemm_core8(a00, a01, a10, a11,
             Bgu + (size_t)eb * (2 * MAT_ELEMS) + (size_t)n0 * 2048,
             32, As_, Bs_, acc);

  short* he = h + (size_t)eb * BT_NUM * 2048;
  const int wm = w >> 2, wn = w & 3;
  const int rr = lane & 15, g4 = lane >> 4;
#pragma unroll
  for (int mi = 0; mi < 8; mi++) {
#pragma unroll
    for (int j = 0; j < 4; j++) {
      const int row = m0 + wm * 128 + (mi >> 2) * 64 + (mi & 3) * 16 + g4 * 4 + j;
      const int tok = idxe[min(row, cm)];
      const float wt = rw[(size_t)tok * 8 + e];
#pragma unroll
      for (int nq = 0; nq < 2; nq++) {
        const float g = acc[mi][nq][j];
        const float u = acc[mi][2 + nq][j];
        const float hv = (g / (1.f + __expf(-g))) * u * wt;
        const int c = (bx * 4 + wn) * 32 + nq * 16 + rr;
        he[(size_t)row * 2048 + c] = f2bf(hv);
      }
    }
  }
}

// ---------------- down, packed: compact bf16 dout (no atomics) ----------------
__global__ __launch_bounds__(512, 1) void down_kernel(
    const short* __restrict__ h, const short* __restrict__ WdT,
    short* __restrict__ dout, const int* __restrict__ cnt)
{
  const int nt = cnt[16];
  if ((int)blockIdx.y >= nt) return;
  const int tl = cnt[32 + blockIdx.y];
  const int e = tl >> 8, by = tl & 255;
  const int cntE = cnt[e];
  const int m0 = by * 256;
  if (m0 >= cntE) return;
  const int bx = blockIdx.x;
  const int n0 = bx * 256;

  __shared__ short As_[32768];
  __shared__ short Bs_[32768];

  const int tid = threadIdx.x;
  const int w = tid >> 6, lane = tid & 63;
  const int l3 = lane >> 3, l7 = lane & 7;
  const size_t swz = (size_t)((l7 ^ l3) * 8);
  const short* he = h + (size_t)e * BT_NUM * 2048;
  const short* a00 = he + (size_t)(m0 + w * 16 + l3) * 2048 + swz;
  const short* a01 = a00 + (size_t)8 * 2048;
  const short* a10 = a00 + (size_t)128 * 2048;
  const short* a11 = a00 + (size_t)136 * 2048;

  f32x4 acc[8][4];
  gemm_core8(a00, a01, a10, a11,
             WdT + (size_t)e * MAT_ELEMS + (size_t)n0 * 2048,
             32, As_, Bs_, acc);

  short* de = dout + (size_t)e * BT_NUM * 2048;
  const int wm = w >> 2, wn = w & 3;
  const int rr = lane & 15, g4 = lane >> 4;
#pragma unroll
  for (int mi = 0; mi < 8; mi++) {
#pragma unroll
    for (int ni = 0; ni < 4; ni++) {
      const int col = n0 + wn * 64 + (ni >> 1) * 32 + (ni & 1) * 16 + rr;
#pragma unroll
      for (int j = 0; j < 4; j++) {
        const int row = m0 + wm * 128 + (mi >> 2) * 64 + (mi & 3) * 16 + g4 * 4 + j;
        de[(size_t)row * 2048 + col] = f2bf(acc[mi][ni][j]);
      }
    }
  }
}

// ---------------- down, fallback: atomic scatter-add (r8) ----------------
__global__ __launch_bounds__(512, 1) void down_atomic_kernel(
    const short* __restrict__ h, const short* __restrict__ WdT,
    float* __restrict__ out,
    const unsigned short* __restrict__ idx, const int* __restrict__ cnt,
    int e_param)
{
  const int e = e_param;
  const int cntE = cnt[e];
  const int by = blockIdx.y, bx = blockIdx.x;
  const int m0 = by * 256;
  if (m0 >= cntE) return;
  const int n0 = bx * 256;
  const unsigned short* idxe = idx + (size_t)e * BT_NUM;

  __shared__ short As_[32768];
  __shared__ short Bs_[32768];

  const int tid = threadIdx.x;
  const int w = tid >> 6, lane = tid & 63;
  const int l3 = lane >> 3, l7 = lane & 7;
  const size_t swz = (size_t)((l7 ^ l3) * 8);
  const short* a00 = h + (size_t)(m0 + w * 16 + l3) * 2048 + swz;
  const short* a01 = a00 + (size_t)8 * 2048;
  const short* a10 = a00 + (size_t)128 * 2048;
  const short* a11 = a00 + (size_t)136 * 2048;

  f32x4 acc[8][4];
  gemm_core8(a00, a01, a10, a11, WdT + (size_t)n0 * 2048, 32, As_, Bs_, acc);

  const int wm = w >> 2, wn = w & 3;
  const int rr = lane & 15, g4 = lane >> 4;
#pragma unroll
  for (int mi = 0; mi < 8; mi++) {
#pragma unroll
    for (int ni = 0; ni < 4; ni++) {
      const int col = n0 + wn * 64 + (ni >> 1) * 32 + (ni & 1) * 16 + rr;
#pragma unroll
      for (int j = 0; j < 4; j++) {
        const int row = m0 + wm * 128 + (mi >> 2) * 64 + (mi & 3) * 16 + g4 * 4 + j;
        if (row < cntE) {
          const int tok = idxe[row];
          unsafeAtomicAdd(&out[(size_t)tok * 2048 + col], acc[mi][ni][j]);
        }
      }
    }
  }
}

// ---------------- combine: out[t] = sum_s dout[inv[t][s]] ----------------
__global__ __launch_bounds__(256) void combine_kernel(
    const short* __restrict__ dout, const unsigned short* __restrict__ inv,
    const unsigned char* __restrict__ invn, float* __restrict__ out)
{
  const int t = blockIdx.x;
  const int nv = invn[t];
  const int c = threadIdx.x * 8;
  float s[8];
#pragma unroll
  for (int j = 0; j < 8; j++) s[j] = 0.f;
  for (int v = 0; v < nv; v++) {
    const unsigned entry = inv[(size_t)t * E_NUM + v];
    const size_t rowoff = ((size_t)(entry >> 12) * BT_NUM + (entry & 4095)) * 2048;
    const short8 d8 = *(const short8*)&dout[rowoff + c];
#pragma unroll
    for (int j = 0; j < 8; j++) s[j] += bf2f(d8[j]);
  }
  float* op = out + (size_t)t * 2048 + c;
  *(f32x4*)op = (f32x4){s[0], s[1], s[2], s[3]};
  *(f32x4*)(op + 4) = (f32x4){s[4], s[5], s[6], s[7]};
}

extern "C" void kernel_launch(void* const* d_in, const int* in_sizes, int n_in,
                              void* d_out, int out_size, void* d_ws, size_t ws_size,
                              hipStream_t stream)
{
  const float* x  = (const float*)d_in[0];
  const float* Wg = (const float*)d_in[1];
  const float* Wu = (const float*)d_in[2];
  const float* Wd = (const float*)d_in[3];
  const float* Wr = (const float*)d_in[4];
  const float* tp = (const float*)d_in[5];
  float* out = (float*)d_out;

  char* ws = (char*)d_ws;
  const size_t SZ_RW   = 131072;
  const size_t SZ_CNT  = 4096;                       // cnt + ntiles + tlist
  const size_t SZ_IDX  = (size_t)E_NUM * BT_NUM * 2;
  const size_t SZ_INV  = (size_t)BT_NUM * E_NUM * 2; // 64 KiB
  const size_t SZ_INVN = 8192;
  const size_t SZ_XB   = (size_t)BT_NUM * 2048 * 2;  // 16 MiB
  const size_t SZ_BGU_E = 2 * MAT_ELEMS * 2;         // 16 MiB
  const size_t SZ_WDT_E = MAT_ELEMS * 2;             // 8 MiB
  const size_t SZ_H_E  = (size_t)BT_NUM * 2048 * 2;  // 16 MiB

  const size_t HEAD = SZ_RW + SZ_CNT + SZ_IDX + SZ_INV + SZ_INVN;
  const size_t FULL = HEAD + SZ_XB + 8 * SZ_BGU_E + 8 * SZ_WDT_E + 8 * SZ_H_E;

  float* rw = (float*)ws;
  int* cnt = (int*)(ws + SZ_RW);
  unsigned short* idx = (unsigned short*)(ws + SZ_RW + SZ_CNT);
  unsigned short* inv = (unsigned short*)(ws + SZ_RW + SZ_CNT + SZ_IDX);
  unsigned char* invn = (unsigned char*)(ws + SZ_RW + SZ_CNT + SZ_IDX + SZ_INV);
  short* xb = (short*)(ws + HEAD);
  char* rest = ws + HEAD + SZ_XB;

  router_kernel<<<BT_NUM, 256, 0, stream>>>(x, Wr, tp, rw);
  init_cnt_kernel<<<1, 64, 0, stream>>>(cnt);
  build_idx_kernel<<<16, 256, 0, stream>>>(rw, cnt, idx, inv, invn);
  pack_tiles_kernel<<<1, 64, 0, stream>>>(cnt);
  cvt_x_kernel<<<4096, 256, 0, stream>>>(x, xb);

  if (ws_size >= FULL) {
    short* Bgu = (short*)rest;
    short* WdT = (short*)(rest + 8 * SZ_BGU_E);
    short* h   = (short*)(rest + 8 * SZ_BGU_E + 8 * SZ_WDT_E);
    short* dout = Bgu;   // alias: Bgu (128 MiB) dead after fused_gu

    transpose_cvt_kernel<<<dim3(64, 64, 24), dim3(32, 8), 0, stream>>>(
        Wg, Wu, Wd, Bgu, WdT, 8);
    fused_gu_kernel<<<dim3(16, MAXT), 512, 0, stream>>>(
        xb, Bgu, h, rw, idx, cnt, 0, 1);
    down_kernel<<<dim3(8, MAXT), 512, 0, stream>>>(h, WdT, dout, cnt);
    combine_kernel<<<BT_NUM, 256, 0, stream>>>(dout, inv, invn, out);
  } else {
    short* Bgu = (short*)rest;
    short* WdT = (short*)(rest + SZ_BGU_E);
    short* h   = (short*)(rest + SZ_BGU_E + SZ_WDT_E);

    zero_out_kernel<<<8192, 256, 0, stream>>>(out);
    for (int e = 0; e < 8; e++) {
      transpose_cvt_kernel<<<dim3(64, 64, 3), dim3(32, 8), 0, stream>>>(
          Wg + (size_t)e * MAT_ELEMS, Wu + (size_t)e * MAT_ELEMS,
          Wd + (size_t)e * MAT_ELEMS, Bgu, WdT, 1);
      fused_gu_kernel<<<dim3(16, 16), 512, 0, stream>>>(
          xb, Bgu, h, rw, idx, cnt, e, 0);
      down_atomic_kernel<<<dim3(8, 16), 512, 0, stream>>>(
          h, WdT, out, idx, cnt, e);
    }
  }
}

// Round 10
// 612.771 us; speedup vs baseline: 1.4776x; 1.1001x over previous
//
#include <hip/hip_runtime.h>
#include <hip/hip_bf16.h>
#include <math.h>

// GoldenMoE: B=2,T=2048,D=2048,E=8,F=2048.
// Round 10: r9 + (a) on-device XCD-bijective swizzle for packed gu/down grids,
// (b) transpose rewritten 64x32 tiles with short2 (128B) writes. Core frozen.

#define E_NUM 8
#define BT_NUM 4096
#define MAT_ELEMS ((size_t)2048 * 2048)
#define MAXT 136

typedef short short8 __attribute__((ext_vector_type(8)));
typedef short short2v __attribute__((ext_vector_type(2)));
typedef float f32x4 __attribute__((ext_vector_type(4)));
typedef __bf16 bf16x8 __attribute__((ext_vector_type(8)));

__device__ __forceinline__ short f2bf(float f) {
  __hip_bfloat16 h = __float2bfloat16(f);
  return __builtin_bit_cast(short, h);
}
__device__ __forceinline__ float bf2f(short s) {
  __hip_bfloat16 h = __builtin_bit_cast(__hip_bfloat16, s);
  return __bfloat162float(h);
}

#define GLOAD_LDS(gptr, lptr) \
  __builtin_amdgcn_global_load_lds( \
      (const __attribute__((address_space(1))) unsigned int*)(gptr), \
      (__attribute__((address_space(3))) unsigned int*)(lptr), 16, 0, 0)

#define LDS_OFF(p) ((unsigned)(size_t)(__attribute__((address_space(3))) const short*)(p))

#define DS_READ_B128(d, a) \
  asm volatile("ds_read_b128 %0, %1" : "=v"(d) : "v"(a))

#define BAR() __builtin_amdgcn_s_barrier()
#define LGKM0() do { \
  asm volatile("s_waitcnt lgkmcnt(0)" ::: "memory"); \
  __builtin_amdgcn_sched_barrier(0); \
} while (0)
#define VMC(n) asm volatile("s_waitcnt vmcnt(" #n ")" ::: "memory")

// XCD-bijective unmap: dispatch id o in [0,nact) -> logical block l.
__device__ __forceinline__ int xcd_unmap(int o, int nact) {
  const int q = nact >> 3, rr = nact & 7;
  const int xcd = o & 7, seq = o >> 3;
  return (xcd < rr) ? xcd * (q + 1) + seq
                    : rr * (q + 1) + (xcd - rr) * q + seq;
}

// ---------------- router ----------------
__global__ __launch_bounds__(256) void router_kernel(
    const float* __restrict__ x, const float* __restrict__ Wr,
    const float* __restrict__ temp, float* __restrict__ rw)
{
  const int bt = blockIdx.x;
  const int tid = threadIdx.x;
  const float* xp = x + (size_t)bt * 2048;
  float acc[E_NUM];
#pragma unroll
  for (int e = 0; e < E_NUM; e++) acc[e] = 0.f;
  for (int d = tid; d < 2048; d += 256) {
    float xv = xp[d];
    const float* wr = Wr + (size_t)d * E_NUM;
#pragma unroll
    for (int e = 0; e < E_NUM; e++) acc[e] += xv * wr[e];
  }
#pragma unroll
  for (int e = 0; e < E_NUM; e++) {
    float v = acc[e];
#pragma unroll
    for (int off = 32; off > 0; off >>= 1) v += __shfl_down(v, off, 64);
    acc[e] = v;
  }
  __shared__ float part[4][E_NUM];
  const int wid = tid >> 6, lane = tid & 63;
  if (lane == 0) {
#pragma unroll
    for (int e = 0; e < E_NUM; e++) part[wid][e] = acc[e];
  }
  __syncthreads();
  if (tid == 0) {
    const float t = temp[0];
    float wz[E_NUM], fb[E_NUM];
    float wsum = 0.f;
#pragma unroll
    for (int e = 0; e < E_NUM; e++) {
      float l = part[0][e] + part[1][e] + part[2][e] + part[3][e];
      float ih = 1.f / (1.f + expf(-l / t));
      float ds = fabsf(ih - 0.36787944117144233f);
      float in_zone = (ih >= 0.21231792754821915f && ih <= 0.5f) ? 1.f : 0.f;
      wz[e] = expf(-ds / 0.1f) * in_zone;
      wsum += wz[e];
      fb[e] = expf(-ds / 0.3f);
    }
    float w[E_NUM];
    if (wsum < 1e-8f) {
      int i1 = 0;
#pragma unroll
      for (int e = 1; e < E_NUM; e++) if (fb[e] > fb[i1]) i1 = e;
      int i2 = -1;
#pragma unroll
      for (int e = 0; e < E_NUM; e++) if (e != i1 && (i2 < 0 || fb[e] > fb[i2])) i2 = e;
      float s = fmaxf(fb[i1] + fb[i2], 1e-8f);
#pragma unroll
      for (int e = 0; e < E_NUM; e++) w[e] = (e == i1 || e == i2) ? fb[e] / s : 0.f;
    } else {
#pragma unroll
      for (int e = 0; e < E_NUM; e++) w[e] = wz[e];
    }
    float s2 = 0.f;
#pragma unroll
    for (int e = 0; e < E_NUM; e++) s2 += w[e];
    s2 = fmaxf(s2, 1e-8f);
    float inv = 1.f / s2;
#pragma unroll
    for (int e = 0; e < E_NUM; e++) rw[(size_t)bt * E_NUM + e] = w[e] * inv;
  }
}

// ---------------- sparse bookkeeping ----------------
__global__ void init_cnt_kernel(int* __restrict__ cnt) {
  if (threadIdx.x < 32) cnt[threadIdx.x] = 0;
}

__global__ __launch_bounds__(256) void build_idx_kernel(
    const float* __restrict__ rw, int* __restrict__ cnt,
    unsigned short* __restrict__ idx,
    unsigned short* __restrict__ inv, unsigned char* __restrict__ invn)
{
  const int t = blockIdx.x * 256 + threadIdx.x;
  const float* w = rw + (size_t)t * E_NUM;
  int s = 0;
#pragma unroll
  for (int e = 0; e < E_NUM; e++) {
    if (w[e] != 0.f) {
      int p = atomicAdd(&cnt[e], 1);
      idx[(size_t)e * BT_NUM + p] = (unsigned short)t;
      inv[(size_t)t * E_NUM + s] = (unsigned short)((e << 12) | p);
      s++;
    }
  }
  invn[t] = (unsigned char)s;
}

__global__ void pack_tiles_kernel(int* __restrict__ cnt) {
  if (threadIdx.x == 0) {
    int n = 0;
    for (int e = 0; e < E_NUM; e++) {
      const int nt = (cnt[e] + 255) >> 8;
      for (int by = 0; by < nt; by++) cnt[32 + n++] = (e << 8) | by;
    }
    cnt[16] = n;
  }
}

__global__ __launch_bounds__(256) void zero_out_kernel(float* __restrict__ out) {
  const size_t i = ((size_t)blockIdx.x * 256 + threadIdx.x) * 4;
  *(f32x4*)(out + i) = (f32x4){0.f, 0.f, 0.f, 0.f};
}

// ---------------- x f32 -> bf16 ----------------
__global__ __launch_bounds__(256) void cvt_x_kernel(
    const float* __restrict__ x, short* __restrict__ xb)
{
  const size_t base = ((size_t)blockIdx.x * 256 + threadIdx.x) * 8;
  f32x4 v0 = *(const f32x4*)(x + base);
  f32x4 v1 = *(const f32x4*)(x + base + 4);
  short8 p;
#pragma unroll
  for (int j = 0; j < 4; j++) { p[j] = f2bf(v0[j]); p[4 + j] = f2bf(v1[j]); }
  *(short8*)(xb + base) = p;
}

// ------------- transpose + f32->bf16 (64x32 input tile, short2 writes) -------------
// which 0:Wg 1:Wu -> B' rows np=(col>>5)*64+which*32+(col&31), per-expert block.
// which 2:Wd -> per-expert WdT[e][n][k]. Output cols = input rows (write 2/thread).
__global__ __launch_bounds__(256) void transpose_cvt_kernel(
    const float* __restrict__ sg, const float* __restrict__ su, const float* __restrict__ sd,
    short* __restrict__ dgu, short* __restrict__ dd, int nexp)
{
  const int which = blockIdx.z / nexp, e = blockIdx.z % nexp;
  __shared__ float t[32][65];
  const int tx = threadIdx.x, ty = threadIdx.y;
  const int x0 = blockIdx.x * 32, y0 = blockIdx.y * 64;
  const float* s = (which == 0 ? sg : which == 1 ? su : sd) + (size_t)e * MAT_ELEMS;
#pragma unroll
  for (int i = 0; i < 8; i++)
    t[tx][ty + 8 * i] = s[(size_t)(y0 + ty + 8 * i) * 2048 + x0 + tx];
  __syncthreads();
  if (which < 2) {
    short* d = dgu + (size_t)e * (2 * MAT_ELEMS);
#pragma unroll
    for (int i = 0; i < 4; i++) {
      const int row = ty + 8 * i;
      const int col = x0 + row;
      const int np = ((col >> 5) * 64) + which * 32 + (col & 31);
      short2v v = {f2bf(t[row][2 * tx]), f2bf(t[row][2 * tx + 1])};
      *(short2v*)&d[(size_t)np * 2048 + y0 + 2 * tx] = v;
    }
  } else {
#pragma unroll
    for (int i = 0; i < 4; i++) {
      const int row = ty + 8 * i;
      short2v v = {f2bf(t[row][2 * tx]), f2bf(t[row][2 * tx + 1])};
      *(short2v*)&dd[(size_t)e * MAT_ELEMS + (size_t)(x0 + row) * 2048 + y0 + 2 * tx] = v;
    }
  }
}

// ================= 256x256 GEMM core, BK=64, 8 waves, 8-phase =================
__device__ __forceinline__ void gemm_core8(
    const short* a00, const short* a01, const short* a10, const short* a11,
    const short* __restrict__ Bb, const int T,
    short* As, short* Bs, f32x4 (&acc)[8][4])
{
  const int tid = threadIdx.x;
  const int w = tid >> 6, lane = tid & 63;
  const int wm = w >> 2, wn = w & 3;
  const int r = lane & 15, g4 = lane >> 4;
  const int l3 = lane >> 3, l7 = lane & 7;

  const size_t bOff = (size_t)(w * 16 + l3) * 2048 + (size_t)((l7 ^ l3) * 8);
  const int wdst = w * 1024;

  const unsigned aB = LDS_OFF(As), bB = LDS_OFF(Bs);
  unsigned aro[2][4], bro[2][2], csb[2];
#pragma unroll
  for (int mh = 0; mh < 2; mh++)
#pragma unroll
    for (int mq = 0; mq < 4; mq++)
      aro[mh][mq] = aB + (unsigned)(wm * 16384 + (mh * 64 + mq * 16 + r) * 128);
#pragma unroll
  for (int nh = 0; nh < 2; nh++)
#pragma unroll
    for (int nq = 0; nq < 2; nq++) {
      const int row = wn * 64 + nh * 32 + nq * 16 + r;
      bro[nh][nq] = bB + (unsigned)((row >> 7) * 16384 + (row & 127) * 128);
    }
#pragma unroll
  for (int kk = 0; kk < 2; kk++)
    csb[kk] = (unsigned)((((kk * 4 + g4) ^ (r & 7)) * 16));

#pragma unroll
  for (int i = 0; i < 8; i++)
#pragma unroll
    for (int jn = 0; jn < 4; jn++) acc[i][jn] = (f32x4){0.f, 0.f, 0.f, 0.f};

#define STG_A(tt, hh) do { \
  const short* g0_ = ((hh) ? a10 : a00) + (tt) * 64; \
  const short* g1_ = ((hh) ? a11 : a01) + (tt) * 64; \
  short* ld_ = As + ((tt) & 1) * 16384 + (hh) * 8192 + wdst; \
  GLOAD_LDS(g0_, ld_); GLOAD_LDS(g1_, ld_ + 512); \
} while (0)

#define STG_B(tt, hh) do { \
  const short* g_ = Bb + bOff + (size_t)(hh) * 128 * 2048 + (tt) * 64; \
  short* ld_ = Bs + ((tt) & 1) * 16384 + (hh) * 8192 + wdst; \
  GLOAD_LDS(g_, ld_); GLOAD_LDS(g_ + (size_t)8 * 2048, ld_ + 512); \
} while (0)

#define RD_A(mh, b32) do { \
  _Pragma("unroll") \
  for (int mq = 0; mq < 4; mq++) \
    _Pragma("unroll") \
    for (int kk = 0; kk < 2; kk++) \
      DS_READ_B128(Ar[mq * 2 + kk], aro[mh][mq] + (b32) + csb[kk]); \
} while (0)

#define RD_B(nh, DST, b32) do { \
  _Pragma("unroll") \
  for (int nq = 0; nq < 2; nq++) \
    _Pragma("unroll") \
    for (int kk = 0; kk < 2; kk++) \
      DS_READ_B128(DST[nq * 2 + kk], bro[nh][nq] + (b32) + csb[kk]); \
} while (0)

#define MM(BV, mh, nh) do { \
  __builtin_amdgcn_s_setprio(1); \
  _Pragma("unroll") \
  for (int kk = 0; kk < 2; kk++) \
    _Pragma("unroll") \
    for (int mq = 0; mq < 4; mq++) \
      _Pragma("unroll") \
      for (int nq = 0; nq < 2; nq++) \
        acc[(mh) * 4 + mq][(nh) * 2 + nq] = \
            __builtin_amdgcn_mfma_f32_16x16x32_bf16( \
                __builtin_bit_cast(bf16x8, Ar[mq * 2 + kk]), \
                __builtin_bit_cast(bf16x8, BV[nq * 2 + kk]), \
                acc[(mh) * 4 + mq][(nh) * 2 + nq], 0, 0, 0); \
  __builtin_amdgcn_s_setprio(0); \
} while (0)

  STG_B(0, 0); STG_B(0, 1);
  STG_A(0, 0); STG_A(0, 1);
  STG_B(1, 0); STG_B(1, 1);
  VMC(4);
  BAR();

  short8 Ar[8], B0[4], B1[4];

  for (int t = 0; t < T; t += 2) {
    const int t1 = t + 1;
    const int t2 = (t + 2 < T) ? t + 2 : 0;
    const int t3 = (t + 3 < T) ? t + 3 : 1;
    // P1
    RD_A(0, 0u); RD_B(0, B0, 0u);
    STG_A(t1, 0);
    BAR(); LGKM0(); MM(B0, 0, 0); BAR();
    // P2
    RD_B(1, B1, 0u);
    STG_A(t1, 1);
    BAR(); LGKM0(); MM(B1, 0, 1); BAR();
    // P3
    RD_A(1, 0u);
    STG_B(t2, 0);
    BAR(); LGKM0(); MM(B0, 1, 0); BAR();
    // P4
    STG_B(t2, 1);
    BAR(); MM(B1, 1, 1);
    VMC(4);
    BAR();
    // P5
    RD_A(0, 32768u); RD_B(0, B0, 32768u);
    STG_A(t2, 0);
    BAR(); LGKM0(); MM(B0, 0, 0); BAR();
    // P6
    RD_B(1, B1, 32768u);
    STG_A(t2, 1);
    BAR(); LGKM0(); MM(B1, 0, 1); BAR();
    // P7
    RD_A(1, 32768u);
    STG_B(t3, 0);
    BAR(); LGKM0(); MM(B0, 1, 0); BAR();
    // P8
    STG_B(t3, 1);
    BAR(); MM(B1, 1, 1);
    VMC(4);
    BAR();
  }
  VMC(0);
#undef STG_A
#undef STG_B
#undef RD_A
#undef RD_B
#undef MM
  __builtin_amdgcn_sched_barrier(0);
  asm volatile("s_nop 7\n\ts_nop 7" ::: "memory");
}

// ---------------- fused gate+up (gathered A, compact h') ----------------
__global__ __launch_bounds__(512, 1) void fused_gu_kernel(
    const short* __restrict__ xb, const short* __restrict__ Bgu,
    short* __restrict__ h, const float* __restrict__ rw,
    const unsigned short* __restrict__ idx, const int* __restrict__ cnt,
    int e_param, int packed)
{
  int e, by, bx, eb;
  if (packed) {
    const int nt = cnt[16];
    const int nact = nt * 16;
    const int o = blockIdx.y * 16 + blockIdx.x;
    if (o >= nact) return;
    const int l = xcd_unmap(o, nact);
    const int tl = cnt[32 + (l >> 4)];
    e = tl >> 8; by = tl & 255; bx = l & 15; eb = e;
  } else {
    e = e_param; by = blockIdx.y; bx = blockIdx.x; eb = 0;
  }
  const int cntE = cnt[e];
  const int m0 = by * 256;
  if (m0 >= cntE) return;
  const int n0 = bx * 256;
  const unsigned short* idxe = idx + (size_t)e * BT_NUM;

  __shared__ short As_[32768];
  __shared__ short Bs_[32768];

  const int tid = threadIdx.x;
  const int w = tid >> 6, lane = tid & 63;
  const int l3 = lane >> 3, l7 = lane & 7;
  const int r0 = m0 + w * 16 + l3;
  const int cm = cntE - 1;
  const size_t swz = (size_t)((l7 ^ l3) * 8);
  const short* a00 = xb + (size_t)idxe[min(r0, cm)] * 2048 + swz;
  const short* a01 = xb + (size_t)idxe[min(r0 + 8, cm)] * 2048 + swz;
  const short* a10 = xb + (size_t)idxe[min(r0 + 128, cm)] * 2048 + swz;
  const short* a11 = xb + (size_t)idxe[min(r0 + 136, cm)] * 2048 + swz;

  f32x4 acc[8][4];
  gemm_core8(a00, a01, a10, a11,
             Bgu + (size_t)eb * (2 * MAT_ELEMS) + (size_t)n0 * 2048,
             32, As_, Bs_, acc);

  short* he = h + (size_t)eb * BT_NUM * 2048;
  const int wm = w >> 2, wn = w & 3;
  const int rr = lane & 15, g4 = lane >> 4;
#pragma unroll
  for (int mi = 0; mi < 8; mi++) {
#pragma unroll
    for (int j = 0; j < 4; j++) {
      const int row = m0 + wm * 128 + (mi >> 2) * 64 + (mi & 3) * 16 + g4 * 4 + j;
      const int tok = idxe[min(row, cm)];
      const float wt = rw[(size_t)tok * 8 + e];
#pragma unroll
      for (int nq = 0; nq < 2; nq++) {
        const float g = acc[mi][nq][j];
        const float u = acc[mi][2 + nq][j];
        const float hv = (g / (1.f + __expf(-g))) * u * wt;
        const int c = (bx * 4 + wn) * 32 + nq * 16 + rr;
        he[(size_t)row * 2048 + c] = f2bf(hv);
      }
    }
  }
}

// ---------------- down, packed: compact bf16 dout (no atomics) ----------------
__global__ __launch_bounds__(512, 1) void down_kernel(
    const short* __restrict__ h, const short* __restrict__ WdT,
    short* __restrict__ dout, const int* __restrict__ cnt)
{
  const int nt = cnt[16];
  const int nact = nt * 8;
  const int o = blockIdx.y * 8 + blockIdx.x;
  if (o >= nact) return;
  const int l = xcd_unmap(o, nact);
  const int tl = cnt[32 + (l >> 3)];
  const int e = tl >> 8, by = tl & 255, bx = l & 7;
  const int cntE = cnt[e];
  const int m0 = by * 256;
  if (m0 >= cntE) return;
  const int n0 = bx * 256;

  __shared__ short As_[32768];
  __shared__ short Bs_[32768];

  const int tid = threadIdx.x;
  const int w = tid >> 6, lane = tid & 63;
  const int l3 = lane >> 3, l7 = lane & 7;
  const size_t swz = (size_t)((l7 ^ l3) * 8);
  const short* he = h + (size_t)e * BT_NUM * 2048;
  const short* a00 = he + (size_t)(m0 + w * 16 + l3) * 2048 + swz;
  const short* a01 = a00 + (size_t)8 * 2048;
  const short* a10 = a00 + (size_t)128 * 2048;
  const short* a11 = a00 + (size_t)136 * 2048;

  f32x4 acc[8][4];
  gemm_core8(a00, a01, a10, a11,
             WdT + (size_t)e * MAT_ELEMS + (size_t)n0 * 2048,
             32, As_, Bs_, acc);

  short* de = dout + (size_t)e * BT_NUM * 2048;
  const int wm = w >> 2, wn = w & 3;
  const int rr = lane & 15, g4 = lane >> 4;
#pragma unroll
  for (int mi = 0; mi < 8; mi++) {
#pragma unroll
    for (int ni = 0; ni < 4; ni++) {
      const int col = n0 + wn * 64 + (ni >> 1) * 32 + (ni & 1) * 16 + rr;
#pragma unroll
      for (int j = 0; j < 4; j++) {
        const int row = m0 + wm * 128 + (mi >> 2) * 64 + (mi & 3) * 16 + g4 * 4 + j;
        de[(size_t)row * 2048 + col] = f2bf(acc[mi][ni][j]);
      }
    }
  }
}

// ---------------- down, fallback: atomic scatter-add ----------------
__global__ __launch_bounds__(512, 1) void down_atomic_kernel(
    const short* __restrict__ h, const short* __restrict__ WdT,
    float* __restrict__ out,
    const unsigned short* __restrict__ idx, const int* __restrict__ cnt,
    int e_param)
{
  const int e = e_param;
  const int cntE = cnt[e];
  const int by = blockIdx.y, bx = blockIdx.x;
  const int m0 = by * 256;
  if (m0 >= cntE) return;
  const int n0 = bx * 256;
  const unsigned short* idxe = idx + (size_t)e * BT_NUM;

  __shared__ short As_[32768];
  __shared__ short Bs_[32768];

  const int tid = threadIdx.x;
  const int w = tid >> 6, lane = tid & 63;
  const int l3 = lane >> 3, l7 = lane & 7;
  const size_t swz = (size_t)((l7 ^ l3) * 8);
  const short* a00 = h + (size_t)(m0 + w * 16 + l3) * 2048 + swz;
  const short* a01 = a00 + (size_t)8 * 2048;
  const short* a10 = a00 + (size_t)128 * 2048;
  const short* a11 = a00 + (size_t)136 * 2048;

  f32x4 acc[8][4];
  gemm_core8(a00, a01, a10, a11, WdT + (size_t)n0 * 2048, 32, As_, Bs_, acc);

  const int wm = w >> 2, wn = w & 3;
  const int rr = lane & 15, g4 = lane >> 4;
#pragma unroll
  for (int mi = 0; mi < 8; mi++) {
#pragma unroll
    for (int ni = 0; ni < 4; ni++) {
      const int col = n0 + wn * 64 + (ni >> 1) * 32 + (ni & 1) * 16 + rr;
#pragma unroll
      for (int j = 0; j < 4; j++) {
        const int row = m0 + wm * 128 + (mi >> 2) * 64 + (mi & 3) * 16 + g4 * 4 + j;
        if (row < cntE) {
          const int tok = idxe[row];
          unsafeAtomicAdd(&out[(size_t)tok * 2048 + col], acc[mi][ni][j]);
        }
      }
    }
  }
}

// ---------------- combine ----------------
__global__ __launch_bounds__(256) void combine_kernel(
    const short* __restrict__ dout, const unsigned short* __restrict__ inv,
    const unsigned char* __restrict__ invn, float* __restrict__ out)
{
  const int t = blockIdx.x;
  const int nv = invn[t];
  const int c = threadIdx.x * 8;
  float s[8];
#pragma unroll
  for (int j = 0; j < 8; j++) s[j] = 0.f;
  for (int v = 0; v < nv; v++) {
    const unsigned entry = inv[(size_t)t * E_NUM + v];
    const size_t rowoff = ((size_t)(entry >> 12) * BT_NUM + (entry & 4095)) * 2048;
    const short8 d8 = *(const short8*)&dout[rowoff + c];
#pragma unroll
    for (int j = 0; j < 8; j++) s[j] += bf2f(d8[j]);
  }
  float* op = out + (size_t)t * 2048 + c;
  *(f32x4*)op = (f32x4){s[0], s[1], s[2], s[3]};
  *(f32x4*)(op + 4) = (f32x4){s[4], s[5], s[6], s[7]};
}

extern "C" void kernel_launch(void* const* d_in, const int* in_sizes, int n_in,
                              void* d_out, int out_size, void* d_ws, size_t ws_size,
                              hipStream_t stream)
{
  const float* x  = (const float*)d_in[0];
  const float* Wg = (const float*)d_in[1];
  const float* Wu = (const float*)d_in[2];
  const float* Wd = (const float*)d_in[3];
  const float* Wr = (const float*)d_in[4];
  const float* tp = (const float*)d_in[5];
  float* out = (float*)d_out;

  char* ws = (char*)d_ws;
  const size_t SZ_RW   = 131072;
  const size_t SZ_CNT  = 4096;
  const size_t SZ_IDX  = (size_t)E_NUM * BT_NUM * 2;
  const size_t SZ_INV  = (size_t)BT_NUM * E_NUM * 2;
  const size_t SZ_INVN = 8192;
  const size_t SZ_XB   = (size_t)BT_NUM * 2048 * 2;
  const size_t SZ_BGU_E = 2 * MAT_ELEMS * 2;
  const size_t SZ_WDT_E = MAT_ELEMS * 2;
  const size_t SZ_H_E  = (size_t)BT_NUM * 2048 * 2;

  const size_t HEAD = SZ_RW + SZ_CNT + SZ_IDX + SZ_INV + SZ_INVN;
  const size_t FULL = HEAD + SZ_XB + 8 * SZ_BGU_E + 8 * SZ_WDT_E + 8 * SZ_H_E;

  float* rw = (float*)ws;
  int* cnt = (int*)(ws + SZ_RW);
  unsigned short* idx = (unsigned short*)(ws + SZ_RW + SZ_CNT);
  unsigned short* inv = (unsigned short*)(ws + SZ_RW + SZ_CNT + SZ_IDX);
  unsigned char* invn = (unsigned char*)(ws + SZ_RW + SZ_CNT + SZ_IDX + SZ_INV);
  short* xb = (short*)(ws + HEAD);
  char* rest = ws + HEAD + SZ_XB;

  router_kernel<<<BT_NUM, 256, 0, stream>>>(x, Wr, tp, rw);
  init_cnt_kernel<<<1, 64, 0, stream>>>(cnt);
  build_idx_kernel<<<16, 256, 0, stream>>>(rw, cnt, idx, inv, invn);
  pack_tiles_kernel<<<1, 64, 0, stream>>>(cnt);
  cvt_x_kernel<<<4096, 256, 0, stream>>>(x, xb);

  if (ws_size >= FULL) {
    short* Bgu = (short*)rest;
    short* WdT = (short*)(rest + 8 * SZ_BGU_E);
    short* h   = (short*)(rest + 8 * SZ_BGU_E + 8 * SZ_WDT_E);
    short* dout = Bgu;   // alias: Bgu dead after fused_gu

    transpose_cvt_kernel<<<dim3(64, 32, 24), dim3(32, 8), 0, stream>>>(
        Wg, Wu, Wd, Bgu, WdT, 8);
    fused_gu_kernel<<<dim3(16, MAXT), 512, 0, stream>>>(
        xb, Bgu, h, rw, idx, cnt, 0, 1);
    down_kernel<<<dim3(8, MAXT), 512, 0, stream>>>(h, WdT, dout, cnt);
    combine_kernel<<<BT_NUM, 256, 0, stream>>>(dout, inv, invn, out);
  } else {
    short* Bgu = (short*)rest;
    short* WdT = (short*)(rest + SZ_BGU_E);
    short* h   = (short*)(rest + SZ_BGU_E + SZ_WDT_E);

    zero_out_kernel<<<8192, 256, 0, stream>>>(out);
    for (int e = 0; e < 8; e++) {
      transpose_cvt_kernel<<<dim3(64, 32, 3), dim3(32, 8), 0, stream>>>(
          Wg + (size_t)e * MAT_ELEMS, Wu + (size_t)e * MAT_ELEMS,
          Wd + (size_t)e * MAT_ELEMS, Bgu, WdT, 1);
      fused_gu_kernel<<<dim3(16, 16), 512, 0, stream>>>(
          xb, Bgu, h, rw, idx, cnt, e, 0);
      down_atomic_kernel<<<dim3(8, 16), 512, 0, stream>>>(
          h, WdT, out, idx, cnt, e);
    }
  }
}